// Round 21
// baseline (192.361 us; speedup 1.0000x reference)
//
#include <hip/hip_runtime.h>
#include <hip/hip_bf16.h>

// CVRPModel: B=16, P=200, N=2000, D=128. Inputs f32, output f32.
// Round 21: T4 counted-vmcnt pipeline in k_score_mfma via inline-asm
// global_load_dwordx4 (compiler can't drain loads it didn't emit).
// 2-deep ping-pong, s_waitcnt vmcnt(12) + sched_barrier(0) per chunk,
// drain vmcnt(0) before epilogue. Rest identical to round 20.

#define BB 16
#define PP 200
#define NN 2000
#define DD 128
#define KPAD 2048
#define AST2 136   // LDS row stride (ushorts): 128+8

typedef __attribute__((ext_vector_type(8))) short short8;
typedef __attribute__((ext_vector_type(4))) float f32x4;
typedef unsigned short ushort_t;

__device__ __forceinline__ ushort_t f2bf(float x){
  union{float f; unsigned int u;} v; v.f = x;
  unsigned int r = v.u + 0x7fffu + ((v.u >> 16) & 1u);
  return (ushort_t)(r >> 16);
}
__device__ __forceinline__ float bf2f(ushort_t h){
  union{unsigned int u; float f;} v; v.u = ((unsigned int)h) << 16; return v.f;
}
// bijective chunked XCD swizzle (nwg % 8 == 0)
__device__ __forceinline__ int xcd_swz(int bid, int nwg){
  return (bid & 7) * (nwg >> 3) + (bid >> 3);
}

// inline-asm 16B global load: compiler does not track its vmcnt.
#define GL16(dst, ptr) \
  asm volatile("global_load_dwordx4 %0, %1, off" : "=&v"(dst) : "v"(ptr))

// ---------------- K1: q projections + sigmoid (unchanged, passing)
__global__ __launch_bounds__(128) void k_qproj(
    const float* __restrict__ q1, const float* __restrict__ q2,
    const float* __restrict__ last, const float* __restrict__ loadv,
    const float* __restrict__ leftv, const float* __restrict__ Wq1,
    const float* __restrict__ Wq2, const float* __restrict__ Wql,
    float* __restrict__ sq_out)
{
  __shared__ float s1[8][DD], s2[8][DD], s3[8][DD];
  const int d = threadIdx.x;
  const int bp0 = blockIdx.x * 8;
  {
    const float4* g1 = (const float4*)(q1 + (size_t)bp0 * DD);
    const float4* g2 = (const float4*)(q2 + (size_t)bp0 * DD);
    const float4* g3 = (const float4*)(last + (size_t)bp0 * DD);
    float4* t1 = (float4*)&s1[0][0];
    float4* t2 = (float4*)&s2[0][0];
    float4* t3 = (float4*)&s3[0][0];
    #pragma unroll
    for (int k = 0; k < 2; k++){
      const int ii = d + k * 128;
      t1[ii] = g1[ii]; t2[ii] = g2[ii]; t3[ii] = g3[ii];
    }
  }
  __syncthreads();
  float acc[8] = {0,0,0,0,0,0,0,0};
  const float4* w1 = (const float4*)(Wq1 + (size_t)d * DD);
  const float4* w2 = (const float4*)(Wq2 + (size_t)d * DD);
  #pragma unroll 8
  for (int i = 0; i < 32; i++){
    const float4 f = w1[i];
    const int e = i * 4;
    #pragma unroll
    for (int r = 0; r < 8; r++)
      acc[r] += s1[r][e]*f.x + s1[r][e+1]*f.y + s1[r][e+2]*f.z + s1[r][e+3]*f.w;
  }
  #pragma unroll 8
  for (int i = 0; i < 32; i++){
    const float4 f = w2[i];
    const int e = i * 4;
    #pragma unroll
    for (int r = 0; r < 8; r++)
      acc[r] += s2[r][e]*f.x + s2[r][e+1]*f.y + s2[r][e+2]*f.z + s2[r][e+3]*f.w;
  }
  const float* wl = Wql + (size_t)d * (DD + 2);
  for (int e = 0; e < DD; e++){
    const float w = wl[e];
    #pragma unroll
    for (int r = 0; r < 8; r++) acc[r] += s3[r][e] * w;
  }
  const float wld = wl[DD], wlf = wl[DD+1];
  #pragma unroll
  for (int r = 0; r < 8; r++){
    const int bp = bp0 + r;
    const float qv = acc[r] + loadv[bp] * wld + leftv[bp] * wlf;
    sq_out[(size_t)bp * DD + d] = 1.f / (1.f + expf(-qv));
  }
}

// ---------------- prep: nodes f32 -> bf16 hi/lo planes, n zero-padded to 2048.
__global__ __launch_bounds__(256) void k_prep_nodes(
    const float* __restrict__ nodes, ushort_t* __restrict__ nh,
    ushort_t* __restrict__ nl)
{
  const int gid = blockIdx.x * 256 + threadIdx.x;
  const int rid = gid >> 4;
  const int d0 = (gid & 15) * 8;
  const int b = rid >> 11, n = rid & 2047;
  float4 v0 = make_float4(0,0,0,0), v1 = make_float4(0,0,0,0);
  if (n < NN){
    const float* src = nodes + ((size_t)b * NN + n) * DD + d0;
    v0 = *(const float4*)src;
    v1 = *(const float4*)(src + 4);
  }
  const float x[8] = {v0.x,v0.y,v0.z,v0.w,v1.x,v1.y,v1.z,v1.w};
  unsigned int h[4], l[4];
  #pragma unroll
  for (int j = 0; j < 4; j++){
    const ushort_t h0 = f2bf(x[2*j]),   h1 = f2bf(x[2*j+1]);
    const ushort_t l0 = f2bf(x[2*j] - bf2f(h0)), l1 = f2bf(x[2*j+1] - bf2f(h1));
    h[j] = (unsigned int)h0 | ((unsigned int)h1 << 16);
    l[j] = (unsigned int)l0 | ((unsigned int)l1 << 16);
  }
  const size_t o = ((size_t)b * KPAD + n) * DD + d0;
  *(uint4*)(nh + o) = make_uint4(h[0],h[1],h[2],h[3]);
  *(uint4*)(nl + o) = make_uint4(l[0],l[1],l[2],l[3]);
}

// ---------------- prep: Wk,Wv -> bf16 hi/lo [mat][c][d]
__global__ __launch_bounds__(256) void k_prep_w(
    const float* __restrict__ Wk, const float* __restrict__ Wv,
    ushort_t* __restrict__ wh, ushort_t* __restrict__ wl)
{
  const int gid = blockIdx.x * 256 + threadIdx.x;
  const int flat = gid * 8;
  const float* W = (flat & 16384) ? Wv : Wk;
  const int idx = flat & 16383;
  const float4 v0 = *(const float4*)(W + idx);
  const float4 v1 = *(const float4*)(W + idx + 4);
  const float x[8] = {v0.x,v0.y,v0.z,v0.w,v1.x,v1.y,v1.z,v1.w};
  unsigned int h[4], l[4];
  #pragma unroll
  for (int j = 0; j < 4; j++){
    const ushort_t h0 = f2bf(x[2*j]),   h1 = f2bf(x[2*j+1]);
    const ushort_t l0 = f2bf(x[2*j] - bf2f(h0)), l1 = f2bf(x[2*j+1] - bf2f(h1));
    h[j] = (unsigned int)h0 | ((unsigned int)h1 << 16);
    l[j] = (unsigned int)l0 | ((unsigned int)l1 << 16);
  }
  *(uint4*)(wh + flat) = make_uint4(h[0],h[1],h[2],h[3]);
  *(uint4*)(wl + flat) = make_uint4(l[0],l[1],l[2],l[3]);
}

// ---------------- K2: ekkT[c][n] via MFMA; 1D grid 256, XCD-swizzled.
__global__ __launch_bounds__(512) void k_kv_mfma(
    const ushort_t* __restrict__ nodes_hi, const ushort_t* __restrict__ nodes_lo,
    const ushort_t* __restrict__ wh, const ushort_t* __restrict__ wlp,
    ushort_t* __restrict__ ekkT_hi, ushort_t* __restrict__ ekkT_lo)
{
  extern __shared__ ushort_t st[];      // [256][136] = 69,632 B
  const int orig = xcd_swz(blockIdx.x, 16 * BB);
  const int b  = orig >> 4;
  const int n0 = (orig & 15) * 128;
  const int tid = threadIdx.x;
  const int w  = tid >> 6, l = tid & 63;
  const int wc = w >> 1;
  const int wn = w & 1;
  const int lr = l & 15;
  const int d0b = (l >> 4) * 8;

  f32x4 acc_k[2][4], acc_v[2][4];
  #pragma unroll
  for (int i = 0; i < 2; i++)
    #pragma unroll
    for (int j = 0; j < 4; j++){
      acc_k[i][j] = (f32x4){0.f,0.f,0.f,0.f};
      acc_v[i][j] = (f32x4){0.f,0.f,0.f,0.f};
    }

  #pragma unroll
  for (int kd = 0; kd < 4; kd++){
    const int d0 = kd * 32 + d0b;
    short8 akh[2], akl[2], avh[2], avl[2];
    #pragma unroll
    for (int tf = 0; tf < 2; tf++){
      const int c = wc * 32 + tf * 16 + lr;
      const size_t wo = (size_t)c * DD + d0;
      akh[tf] = *(const short8*)(wh  + wo);
      akl[tf] = *(const short8*)(wlp + wo);
      avh[tf] = *(const short8*)(wh  + 16384 + wo);
      avl[tf] = *(const short8*)(wlp + 16384 + wo);
    }
    short8 bh[4], bl[4];
    #pragma unroll
    for (int tn = 0; tn < 4; tn++){
      const int n = n0 + wn * 64 + tn * 16 + lr;
      const size_t no = ((size_t)b * KPAD + n) * DD + d0;
      bh[tn] = *(const short8*)(nodes_hi + no);
      bl[tn] = *(const short8*)(nodes_lo + no);
    }
    #pragma unroll
    for (int tf = 0; tf < 2; tf++)
      #pragma unroll
      for (int tn = 0; tn < 4; tn++){
        acc_k[tf][tn] = __builtin_amdgcn_mfma_f32_16x16x32_bf16(akh[tf], bh[tn], acc_k[tf][tn], 0, 0, 0);
        acc_k[tf][tn] = __builtin_amdgcn_mfma_f32_16x16x32_bf16(akh[tf], bl[tn], acc_k[tf][tn], 0, 0, 0);
        acc_k[tf][tn] = __builtin_amdgcn_mfma_f32_16x16x32_bf16(akl[tf], bh[tn], acc_k[tf][tn], 0, 0, 0);
        acc_v[tf][tn] = __builtin_amdgcn_mfma_f32_16x16x32_bf16(avh[tf], bh[tn], acc_v[tf][tn], 0, 0, 0);
        acc_v[tf][tn] = __builtin_amdgcn_mfma_f32_16x16x32_bf16(avh[tf], bl[tn], acc_v[tf][tn], 0, 0, 0);
        acc_v[tf][tn] = __builtin_amdgcn_mfma_f32_16x16x32_bf16(avl[tf], bh[tn], acc_v[tf][tn], 0, 0, 0);
      }
  }
  #pragma unroll
  for (int tf = 0; tf < 2; tf++)
    #pragma unroll
    for (int tn = 0; tn < 4; tn++)
      #pragma unroll
      for (int r = 0; r < 4; r++){
        const float ek = expf(acc_k[tf][tn][r]);
        acc_k[tf][tn][r] = ek;
        acc_v[tf][tn][r] = ek * acc_v[tf][tn][r];
      }
  #pragma unroll
  for (int plane = 0; plane < 2; plane++){
    __syncthreads();
    #pragma unroll
    for (int tf = 0; tf < 2; tf++)
      #pragma unroll
      for (int tn = 0; tn < 4; tn++)
        #pragma unroll
        for (int r = 0; r < 4; r++){
          const int row = wc * 32 + tf * 16 + (l >> 4) * 4 + r;
          const int col = wn * 64 + tn * 16 + lr;
          const float vv = acc_v[tf][tn][r];
          const float vk = acc_k[tf][tn][r];
          const ushort_t hv = f2bf(vv), hk = f2bf(vk);
          st[row * 136 + col]         = plane ? f2bf(vv - bf2f(hv)) : hv;
          st[(row + 128) * 136 + col] = plane ? f2bf(vk - bf2f(hk)) : hk;
        }
    __syncthreads();
    const int row = tid >> 1, seg = tid & 1;
    const uint4* src = (const uint4*)(st + row * 136 + seg * 64);
    ushort_t* dp = (plane ? ekkT_lo : ekkT_hi)
                 + ((size_t)b * 256 + row) * KPAD + n0 + seg * 64;
    uint4* dst4 = (uint4*)dp;
    #pragma unroll
    for (int j = 0; j < 8; j++) dst4[j] = src[j];
  }
}

// ---- k_aft_mfma staging registers + helpers (round-20 version, unchanged)
struct StageRegs { float4 dv[2][2]; float4 nv[2][2]; };

__device__ __forceinline__ void stage_load(
    const float* __restrict__ dist, const float* __restrict__ ninf,
    size_t bbase, int p0, int k0p, int tid, StageRegs& R)
{
  #pragma unroll
  for (int i = 0; i < 2; i++){
    const int flat = tid * 8 + i * 2048;
    const int pl_ = flat >> 7;
    const int kl_ = flat & 127;
    const int pg = p0 + pl_;
    const int kg = k0p + kl_;
    const bool ok = (pg < PP) && (kg + 8 <= NN);
    const size_t o = bbase + (size_t)(ok ? pg : 0) * NN + (ok ? kg : 0);
    R.dv[i][0] = *(const float4*)(dist + o);
    R.dv[i][1] = *(const float4*)(dist + o + 4);
    R.nv[i][0] = *(const float4*)(ninf + o);
    R.nv[i][1] = *(const float4*)(ninf + o + 4);
  }
}

__device__ __forceinline__ void stage_write(
    ushort_t* __restrict__ eh, ushort_t* __restrict__ el, float scale,
    int p0, int k0p, int tid, const StageRegs& R)
{
  #pragma unroll
  for (int i = 0; i < 2; i++){
    const int flat = tid * 8 + i * 2048;
    const int pl_ = flat >> 7;
    const int kl_ = flat & 127;
    const int pg = p0 + pl_;
    const int kg = k0p + kl_;
    const bool ok = (pg < PP) && (kg + 8 <= NN);
    float e[8];
    const float4 da = R.dv[i][0], db = R.dv[i][1];
    const float4 na = R.nv[i][0], nb = R.nv[i][1];
    e[0] = expf(na.x - scale*da.x); e[1] = expf(na.y - scale*da.y);
    e[2] = expf(na.z - scale*da.z); e[3] = expf(na.w - scale*da.w);
    e[4] = expf(nb.x - scale*db.x); e[5] = expf(nb.y - scale*db.y);
    e[6] = expf(nb.z - scale*db.z); e[7] = expf(nb.w - scale*db.w);
    if (!ok){
      #pragma unroll
      for (int j = 0; j < 8; j++) e[j] = 0.f;
    }
    unsigned int hw[4], lw[4];
    #pragma unroll
    for (int j = 0; j < 4; j++){
      const ushort_t h0 = f2bf(e[2*j]),   h1 = f2bf(e[2*j+1]);
      const ushort_t l0 = f2bf(e[2*j] - bf2f(h0)), l1 = f2bf(e[2*j+1] - bf2f(h1));
      hw[j] = (unsigned int)h0 | ((unsigned int)h1 << 16);
      lw[j] = (unsigned int)l0 | ((unsigned int)l1 << 16);
    }
    *(uint4*)(eh + pl_ * AST2 + kl_) = make_uint4(hw[0],hw[1],hw[2],hw[3]);
    *(uint4*)(el + pl_ * AST2 + kl_) = make_uint4(lw[0],lw[1],lw[2],lw[3]);
  }
}

__device__ __forceinline__ void aft_mfma_phase(
    const ushort_t* __restrict__ eh, const ushort_t* __restrict__ el,
    const ushort_t* const bph[4], const ushort_t* const bpl[4],
    int kgbase, int lr, int lk, f32x4 acc[2][4])
{
  #pragma unroll
  for (int kc = 0; kc < 4; kc++){
    const int ko = kc * 32;
    const int kg = kgbase + ko;
    short8 ah[2], al[2], bh[4], bl[4];
    #pragma unroll
    for (int tp = 0; tp < 2; tp++){
      const int row = tp * 16 + lr;
      ah[tp] = *(const short8*)(eh + row * AST2 + lk + ko);
      al[tp] = *(const short8*)(el + row * AST2 + lk + ko);
    }
    #pragma unroll
    for (int tc = 0; tc < 4; tc++){
      bh[tc] = *(const short8*)(bph[tc] + kg);
      bl[tc] = *(const short8*)(bpl[tc] + kg);
    }
    #pragma unroll
    for (int tp = 0; tp < 2; tp++)
      #pragma unroll
      for (int tc = 0; tc < 4; tc++){
        acc[tp][tc] = __builtin_amdgcn_mfma_f32_16x16x32_bf16(ah[tp], bh[tc], acc[tp][tc], 0, 0, 0);
        acc[tp][tc] = __builtin_amdgcn_mfma_f32_16x16x32_bf16(ah[tp], bl[tc], acc[tp][tc], 0, 0, 0);
        acc[tp][tc] = __builtin_amdgcn_mfma_f32_16x16x32_bf16(al[tp], bh[tc], acc[tp][tc], 0, 0, 0);
      }
  }
}

// ---------------- K3a: double-buffered 4-phase e_alpha + MFMA (round-20 version)
__global__ __launch_bounds__(256, 2) void k_aft_mfma(
    const float* __restrict__ dist, const float* __restrict__ ninf,
    const ushort_t* __restrict__ ekkT_hi, const ushort_t* __restrict__ ekkT_lo,
    const float* __restrict__ log_scale, const float* __restrict__ aft_alpha,
    float* __restrict__ partial)
{
  __shared__ ushort_t ea_h0[32 * AST2], ea_l0[32 * AST2];
  __shared__ ushort_t ea_h1[32 * AST2], ea_l1[32 * AST2];
  const int orig = xcd_swz(blockIdx.x, 32 * BB);
  const int b  = orig >> 5;
  const int t  = orig & 31;
  const int mi = t >> 2;
  const int ks = t & 3;
  const int tid = threadIdx.x;
  const int p0 = mi * 32;
  const int k0 = ks * 512;
  const float scale = log_scale[0] * aft_alpha[0];
  const int w  = tid >> 6;
  const int l  = tid & 63;
  const int lr = l & 15;
  const int lk = (l >> 4) * 8;
  const size_t bbase = (size_t)b * PP * NN;

  f32x4 acc[2][4];
  #pragma unroll
  for (int i = 0; i < 2; i++)
    #pragma unroll
    for (int j = 0; j < 4; j++) acc[i][j] = (f32x4){0.f, 0.f, 0.f, 0.f};

  const ushort_t* bph[4];
  const ushort_t* bpl[4];
  #pragma unroll
  for (int tc = 0; tc < 4; tc++){
    const int c = w * 64 + tc * 16 + lr;
    const size_t off = ((size_t)b * 256 + c) * KPAD + k0 + lk;
    bph[tc] = ekkT_hi + off;
    bpl[tc] = ekkT_lo + off;
  }

  StageRegs R;
  stage_load(dist, ninf, bbase, p0, k0, tid, R);
  stage_write(ea_h0, ea_l0, scale, p0, k0, tid, R);
  __syncthreads();

  stage_load(dist, ninf, bbase, p0, k0 + 128, tid, R);
  __builtin_amdgcn_sched_barrier(0);
  aft_mfma_phase(ea_h0, ea_l0, bph, bpl, 0, lr, lk, acc);
  __builtin_amdgcn_sched_barrier(0);
  stage_write(ea_h1, ea_l1, scale, p0, k0 + 128, tid, R);
  __syncthreads();

  stage_load(dist, ninf, bbase, p0, k0 + 256, tid, R);
  __builtin_amdgcn_sched_barrier(0);
  aft_mfma_phase(ea_h1, ea_l1, bph, bpl, 128, lr, lk, acc);
  __builtin_amdgcn_sched_barrier(0);
  stage_write(ea_h0, ea_l0, scale, p0, k0 + 256, tid, R);
  __syncthreads();

  stage_load(dist, ninf, bbase, p0, k0 + 384, tid, R);
  __builtin_amdgcn_sched_barrier(0);
  aft_mfma_phase(ea_h0, ea_l0, bph, bpl, 256, lr, lk, acc);
  __builtin_amdgcn_sched_barrier(0);
  stage_write(ea_h1, ea_l1, scale, p0, k0 + 384, tid, R);
  __syncthreads();

  aft_mfma_phase(ea_h1, ea_l1, bph, bpl, 384, lr, lk, acc);

  #pragma unroll
  for (int tp = 0; tp < 2; tp++){
    const int prow = p0 + tp * 16 + (l >> 4) * 4;
    #pragma unroll
    for (int tc = 0; tc < 4; tc++){
      const int c = w * 64 + tc * 16 + (l & 15);
      #pragma unroll
      for (int r = 0; r < 4; r++){
        partial[(size_t)ks * 1048576 + ((size_t)b * 256 + prow + r) * 256 + c] = acc[tp][tc][r];
      }
    }
  }
}

// ---------------- K3b: reduce 4 partials; aft = sq*bias/(den+eps) -> bf16 hi/lo
__global__ __launch_bounds__(256) void k_aft_reduce(
    const float* __restrict__ partial, const float* __restrict__ sq,
    ushort_t* __restrict__ aft_hi, ushort_t* __restrict__ aft_lo)
{
  const int pl = threadIdx.x >> 7;
  const int c  = threadIdx.x & 127;
  const int b = blockIdx.y;
  #pragma unroll
  for (int i = 0; i < 4; i++){
    const int p = blockIdx.x * 8 + i * 2 + pl;   // 0..255
    float v = 0.f;
    if (p < PP){
      const size_t base = ((size_t)b * 256 + p) * 256;
      float bias = 0.f, den = 0.f;
      #pragma unroll
      for (int ksi = 0; ksi < 4; ksi++){
        const float* ptr = partial + (size_t)ksi * 1048576 + base;
        bias += ptr[c];
        den  += ptr[c + 128];
      }
      v = sq[((size_t)b * PP + p) * DD + c] * (bias / (den + 1e-20f));
    }
    const size_t o = ((size_t)b * 256 + p) * DD + c;
    const ushort_t h = f2bf(v);
    aft_hi[o] = h;
    aft_lo[o] = f2bf(v - bf2f(h));
  }
}

// ---------------- K4a: score via MFMA + max-free softmax numerator.
// T4: inline-asm fragment loads, counted vmcnt, 2-deep ping-pong.
__global__ __launch_bounds__(512, 2) void k_score_mfma(
    const ushort_t* __restrict__ aft_hi, const ushort_t* __restrict__ aft_lo,
    const ushort_t* __restrict__ nodes_hi, const ushort_t* __restrict__ nodes_lo,
    const float* __restrict__ dist, const float* __restrict__ ninf,
    const float* __restrict__ log_scale, const float* __restrict__ probs_alpha,
    float* __restrict__ e_out, float* __restrict__ rowpart)
{
  const int orig = xcd_swz(blockIdx.x, 32 * BB);
  const int b  = orig >> 5;
  const int t  = orig & 31;
  const int mi = t >> 3;              // 0..3
  const int nt = t & 7;               // 0..7
  const int tid = threadIdx.x;
  const int p0 = mi * 64;
  const int n0 = nt * 256;
  const float spb = log_scale[0] * probs_alpha[0];
  const float isd = 0.088388347648318447f;  // 1/sqrt(128)
  const int w  = tid >> 6, l = tid & 63;
  const int wp = w >> 2, wc = w & 3;
  const int lr = l & 15, lk = (l >> 4) * 8;

  f32x4 acc[2][4];
  #pragma unroll
  for (int i = 0; i < 2; i++)
    #pragma unroll
    for (int j = 0; j < 4; j++) acc[i][j] = (f32x4){0.f, 0.f, 0.f, 0.f};

  const ushort_t* aph[2];
  const ushort_t* apl[2];
  #pragma unroll
  for (int tp = 0; tp < 2; tp++){
    const int row = p0 + wp * 32 + tp * 16 + lr;
    const size_t off = ((size_t)b * 256 + row) * DD + lk;
    aph[tp] = aft_hi + off;
    apl[tp] = aft_lo + off;
  }
  const ushort_t* bph[4];
  const ushort_t* bpl[4];
  #pragma unroll
  for (int tc = 0; tc < 4; tc++){
    const int n = n0 + wc * 64 + tc * 16 + lr;
    const size_t off = ((size_t)b * KPAD + n) * DD + lk;
    bph[tc] = nodes_hi + off;
    bpl[tc] = nodes_lo + off;
  }

  // two fragment sets, ping-pong; 12 x 16B asm loads per set
  short8 Aah[2], Aal[2], Abh[4], Abl[4];
  short8 Bah[2], Bal[2], Bbh[4], Bbl[4];

  #define ISSUE_A(KO) do {                                   \
    GL16(Aah[0], aph[0] + (KO)); GL16(Aah[1], aph[1] + (KO));\
    GL16(Aal[0], apl[0] + (KO)); GL16(Aal[1], apl[1] + (KO));\
    GL16(Abh[0], bph[0] + (KO)); GL16(Abh[1], bph[1] + (KO));\
    GL16(Abh[2], bph[2] + (KO)); GL16(Abh[3], bph[3] + (KO));\
    GL16(Abl[0], bpl[0] + (KO)); GL16(Abl[1], bpl[1] + (KO));\
    GL16(Abl[2], bpl[2] + (KO)); GL16(Abl[3], bpl[3] + (KO));\
  } while(0)
  #define ISSUE_B(KO) do {                                   \
    GL16(Bah[0], aph[0] + (KO)); GL16(Bah[1], aph[1] + (KO));\
    GL16(Bal[0], apl[0] + (KO)); GL16(Bal[1], apl[1] + (KO));\
    GL16(Bbh[0], bph[0] + (KO)); GL16(Bbh[1], bph[1] + (KO));\
    GL16(Bbh[2], bph[2] + (KO)); GL16(Bbh[3], bph[3] + (KO));\
    GL16(Bbl[0], bpl[0] + (KO)); GL16(Bbl[1], bpl[1] + (KO));\
    GL16(Bbl[2], bpl[2] + (KO)); GL16(Bbl[3], bpl[3] + (KO));\
  } while(0)
  #define MFMA_SET(ah, al, bh, bl) do {                      \
    _Pragma("unroll")                                        \
    for (int tp = 0; tp < 2; tp++)                           \
      _Pragma("unroll")                                      \
      for (int tc = 0; tc < 4; tc++){                        \
        acc[tp][tc] = __builtin_amdgcn_mfma_f32_16x16x32_bf16(ah[tp], bh[tc], acc[tp][tc], 0, 0, 0); \
        acc[tp][tc] = __builtin_amdgcn_mfma_f32_16x16x32_bf16(ah[tp], bl[tc], acc[tp][tc], 0, 0, 0); \
        acc[tp][tc] = __builtin_amdgcn_mfma_f32_16x16x32_bf16(al[tp], bh[tc], acc[tp][tc], 0, 0, 0); \
        acc[tp][tc] = __builtin_amdgcn_mfma_f32_16x16x32_bf16(al[tp], bl[tc], acc[tp][tc], 0, 0, 0); \
      }                                                      \
  } while(0)

  ISSUE_A(0);                                  // 12 in flight
  ISSUE_B(32);                                 // 24 in flight
  asm volatile("s_waitcnt vmcnt(12)" ::: "memory");   // set A ready
  __builtin_amdgcn_sched_barrier(0);
  MFMA_SET(Aah, Aal, Abh, Abl);
  ISSUE_A(64);                                 // 24 in flight (B + A')
  asm volatile("s_waitcnt vmcnt(12)" ::: "memory");   // set B ready
  __builtin_amdgcn_sched_barrier(0);
  MFMA_SET(Bah, Bal, Bbh, Bbl);
  ISSUE_B(96);                                 // 24 in flight (A' + B')
  asm volatile("s_waitcnt vmcnt(12)" ::: "memory");   // set A' ready
  __builtin_amdgcn_sched_barrier(0);
  MFMA_SET(Aah, Aal, Abh, Abl);
  asm volatile("s_waitcnt vmcnt(0)" ::: "memory");    // drain (B' ready)
  __builtin_amdgcn_sched_barrier(0);
  MFMA_SET(Bah, Bal, Bbh, Bbl);

  #undef ISSUE_A
  #undef ISSUE_B
  #undef MFMA_SET

  // epilogue: e = exp(score - 10); store + per-row (64-col slice) sums.
  #pragma unroll
  for (int tp = 0; tp < 2; tp++){
    #pragma unroll
    for (int r = 0; r < 4; r++){
      const int p = p0 + wp * 32 + tp * 16 + (l >> 4) * 4 + r;
      float rsum = 0.f;
      #pragma unroll
      for (int tc = 0; tc < 4; tc++){
        const int ncol = n0 + wc * 64 + tc * 16 + (l & 15);
        float ev = 0.f;
        if (p < PP && ncol < NN){
          const size_t off = ((size_t)b * PP + p) * NN + ncol;
          const float sc = 10.f * tanhf(acc[tp][tc][r] * isd - spb * dist[off]) + ninf[off];
          ev = expf(sc - 10.f);
          e_out[off] = ev;
        }
        rsum += ev;
      }
      rsum += __shfl_xor(rsum, 1);
      rsum += __shfl_xor(rsum, 2);
      rsum += __shfl_xor(rsum, 4);
      rsum += __shfl_xor(rsum, 8);
      if ((l & 15) == 0 && p < PP)
        rowpart[((size_t)b * 256 + p) * 32 + nt * 4 + wc] = rsum;
    }
  }
}

// ---------------- K4b: scale by 1/rowsum. grid (PP, B) x 256; block = one row.
__global__ __launch_bounds__(256) void k_scale(
    const float* __restrict__ e_in, const float* __restrict__ rowpart,
    float* __restrict__ out)
{
  __shared__ float red[32];
  __shared__ float sinv;
  const int tid = threadIdx.x;
  const int p = blockIdx.x;
  const int b = blockIdx.y;
  if (tid < 32) red[tid] = rowpart[((size_t)b * 256 + p) * 32 + tid];
  __syncthreads();
  if (tid == 0){
    float s = 0.f;
    #pragma unroll
    for (int i = 0; i < 32; i++) s += red[i];
    sinv = 1.f / s;
  }
  __syncthreads();
  const float inv = sinv;
  const float4* src = (const float4*)(e_in + ((size_t)b * PP + p) * NN);
  float4* dst = (float4*)(out + ((size_t)b * PP + p) * NN);
  for (int i = tid; i < NN / 4; i += 256){
    float4 v = src[i];
    v.x *= inv; v.y *= inv; v.z *= inv; v.w *= inv;
    dst[i] = v;
  }
}

extern "C" void kernel_launch(void* const* d_in, const int* in_sizes, int n_in,
                              void* d_out, int out_size, void* d_ws, size_t ws_size,
                              hipStream_t stream)
{
  const float* nodes = (const float*)d_in[0];
  const float* last  = (const float*)d_in[1];
  const float* q1    = (const float*)d_in[2];
  const float* q2    = (const float*)d_in[3];
  const float* loadv = (const float*)d_in[4];
  const float* leftv = (const float*)d_in[5];
  const float* dist  = (const float*)d_in[6];
  const float* ninf  = (const float*)d_in[7];
  const float* ls    = (const float*)d_in[8];
  const float* Wq1   = (const float*)d_in[9];
  const float* Wq2   = (const float*)d_in[10];
  const float* Wql   = (const float*)d_in[11];
  const float* Wk    = (const float*)d_in[12];
  const float* Wv    = (const float*)d_in[13];
  const float* aa    = (const float*)d_in[14];
  const float* pa    = (const float*)d_in[15];
  float* out = (float*)d_out;

  char* wsb = (char*)d_ws;
  float*    sq       = (float*)(wsb);                 // 1,638,400 B
  ushort_t* aft_hi   = (ushort_t*)(wsb + 1638400);    // 1,048,576 B
  ushort_t* aft_lo   = (ushort_t*)(wsb + 2686976);    // 1,048,576 B
  ushort_t* ekkT_hi  = (ushort_t*)(wsb + 3735552);    // 16,777,216 B
  ushort_t* ekkT_lo  = (ushort_t*)(wsb + 20512768);   // 16,777,216 B
  ushort_t* nodes_hi = (ushort_t*)(wsb + 37289984);   //  8,388,608 B
  ushort_t* nodes_lo = (ushort_t*)(wsb + 45678592);   //  8,388,608 B
  ushort_t* w_hi     = (ushort_t*)(wsb + 54067200);   //     65,536 B
  ushort_t* w_lo     = (ushort_t*)(wsb + 54132736);   //     65,536 B
  float*    partial  = (float*)(wsb + 54198272);      // 16,777,216 B [4][16][256][256]
  float*    e_buf    = partial;                       // 25,600,000 B (partial dead)
  float*    rowpart  = (float*)(wsb + 79798272);      //    524,288 B

  k_qproj<<<dim3((BB * PP) / 8), dim3(128), 0, stream>>>(q1, q2, last, loadv, leftv, Wq1, Wq2, Wql, sq);
  k_prep_nodes<<<dim3(2048), dim3(256), 0, stream>>>(nodes, nodes_hi, nodes_lo);
  k_prep_w<<<dim3(16), dim3(256), 0, stream>>>(Wk, Wv, w_hi, w_lo);
  k_kv_mfma<<<dim3(16 * BB), dim3(512), 69632, stream>>>(nodes_hi, nodes_lo, w_hi, w_lo, ekkT_hi, ekkT_lo);
  k_aft_mfma<<<dim3(32 * BB), dim3(256), 0, stream>>>(dist, ninf, ekkT_hi, ekkT_lo, ls, aa, partial);
  k_aft_reduce<<<dim3(32, BB), dim3(256), 0, stream>>>(partial, sq, aft_hi, aft_lo);
  k_score_mfma<<<dim3(32 * BB), dim3(512), 0, stream>>>(aft_hi, aft_lo, nodes_hi, nodes_lo, dist, ninf, ls, pa, e_buf, rowpart);
  k_scale<<<dim3(PP, BB), dim3(256), 0, stream>>>(e_buf, rowpart, out);
}

// Round 22
// 160.146 us; speedup vs baseline: 1.2012x; 1.2012x over previous
//
#include <hip/hip_runtime.h>
#include <hip/hip_bf16.h>

// CVRPModel: B=16, P=200, N=2000, D=128. Inputs f32, output f32.
// Round 22: k_score split -> pure GEMM (MFMA + f32 store, round-20 loads,
// XCD swizzle) + k_scale_fused (tanh/exp/mask + softmax normalize, one row
// per block, fully coalesced float4 streaming; row e[] staged in 8KB LDS).
// T4-asm reverted (regressed). aft/kv unchanged from round 20.

#define BB 16
#define PP 200
#define NN 2000
#define DD 128
#define KPAD 2048
#define AST2 136   // LDS row stride (ushorts): 128+8

typedef __attribute__((ext_vector_type(8))) short short8;
typedef __attribute__((ext_vector_type(4))) float f32x4;
typedef unsigned short ushort_t;

__device__ __forceinline__ ushort_t f2bf(float x){
  union{float f; unsigned int u;} v; v.f = x;
  unsigned int r = v.u + 0x7fffu + ((v.u >> 16) & 1u);
  return (ushort_t)(r >> 16);
}
__device__ __forceinline__ float bf2f(ushort_t h){
  union{unsigned int u; float f;} v; v.u = ((unsigned int)h) << 16; return v.f;
}
// bijective chunked XCD swizzle (nwg % 8 == 0)
__device__ __forceinline__ int xcd_swz(int bid, int nwg){
  return (bid & 7) * (nwg >> 3) + (bid >> 3);
}

// ---------------- K1: q projections + sigmoid (unchanged, passing)
__global__ __launch_bounds__(128) void k_qproj(
    const float* __restrict__ q1, const float* __restrict__ q2,
    const float* __restrict__ last, const float* __restrict__ loadv,
    const float* __restrict__ leftv, const float* __restrict__ Wq1,
    const float* __restrict__ Wq2, const float* __restrict__ Wql,
    float* __restrict__ sq_out)
{
  __shared__ float s1[8][DD], s2[8][DD], s3[8][DD];
  const int d = threadIdx.x;
  const int bp0 = blockIdx.x * 8;
  {
    const float4* g1 = (const float4*)(q1 + (size_t)bp0 * DD);
    const float4* g2 = (const float4*)(q2 + (size_t)bp0 * DD);
    const float4* g3 = (const float4*)(last + (size_t)bp0 * DD);
    float4* t1 = (float4*)&s1[0][0];
    float4* t2 = (float4*)&s2[0][0];
    float4* t3 = (float4*)&s3[0][0];
    #pragma unroll
    for (int k = 0; k < 2; k++){
      const int ii = d + k * 128;
      t1[ii] = g1[ii]; t2[ii] = g2[ii]; t3[ii] = g3[ii];
    }
  }
  __syncthreads();
  float acc[8] = {0,0,0,0,0,0,0,0};
  const float4* w1 = (const float4*)(Wq1 + (size_t)d * DD);
  const float4* w2 = (const float4*)(Wq2 + (size_t)d * DD);
  #pragma unroll 8
  for (int i = 0; i < 32; i++){
    const float4 f = w1[i];
    const int e = i * 4;
    #pragma unroll
    for (int r = 0; r < 8; r++)
      acc[r] += s1[r][e]*f.x + s1[r][e+1]*f.y + s1[r][e+2]*f.z + s1[r][e+3]*f.w;
  }
  #pragma unroll 8
  for (int i = 0; i < 32; i++){
    const float4 f = w2[i];
    const int e = i * 4;
    #pragma unroll
    for (int r = 0; r < 8; r++)
      acc[r] += s2[r][e]*f.x + s2[r][e+1]*f.y + s2[r][e+2]*f.z + s2[r][e+3]*f.w;
  }
  const float* wl = Wql + (size_t)d * (DD + 2);
  for (int e = 0; e < DD; e++){
    const float w = wl[e];
    #pragma unroll
    for (int r = 0; r < 8; r++) acc[r] += s3[r][e] * w;
  }
  const float wld = wl[DD], wlf = wl[DD+1];
  #pragma unroll
  for (int r = 0; r < 8; r++){
    const int bp = bp0 + r;
    const float qv = acc[r] + loadv[bp] * wld + leftv[bp] * wlf;
    sq_out[(size_t)bp * DD + d] = 1.f / (1.f + expf(-qv));
  }
}

// ---------------- prep: nodes f32 -> bf16 hi/lo planes, n zero-padded to 2048.
__global__ __launch_bounds__(256) void k_prep_nodes(
    const float* __restrict__ nodes, ushort_t* __restrict__ nh,
    ushort_t* __restrict__ nl)
{
  const int gid = blockIdx.x * 256 + threadIdx.x;
  const int rid = gid >> 4;
  const int d0 = (gid & 15) * 8;
  const int b = rid >> 11, n = rid & 2047;
  float4 v0 = make_float4(0,0,0,0), v1 = make_float4(0,0,0,0);
  if (n < NN){
    const float* src = nodes + ((size_t)b * NN + n) * DD + d0;
    v0 = *(const float4*)src;
    v1 = *(const float4*)(src + 4);
  }
  const float x[8] = {v0.x,v0.y,v0.z,v0.w,v1.x,v1.y,v1.z,v1.w};
  unsigned int h[4], l[4];
  #pragma unroll
  for (int j = 0; j < 4; j++){
    const ushort_t h0 = f2bf(x[2*j]),   h1 = f2bf(x[2*j+1]);
    const ushort_t l0 = f2bf(x[2*j] - bf2f(h0)), l1 = f2bf(x[2*j+1] - bf2f(h1));
    h[j] = (unsigned int)h0 | ((unsigned int)h1 << 16);
    l[j] = (unsigned int)l0 | ((unsigned int)l1 << 16);
  }
  const size_t o = ((size_t)b * KPAD + n) * DD + d0;
  *(uint4*)(nh + o) = make_uint4(h[0],h[1],h[2],h[3]);
  *(uint4*)(nl + o) = make_uint4(l[0],l[1],l[2],l[3]);
}

// ---------------- prep: Wk,Wv -> bf16 hi/lo [mat][c][d]
__global__ __launch_bounds__(256) void k_prep_w(
    const float* __restrict__ Wk, const float* __restrict__ Wv,
    ushort_t* __restrict__ wh, ushort_t* __restrict__ wl)
{
  const int gid = blockIdx.x * 256 + threadIdx.x;
  const int flat = gid * 8;
  const float* W = (flat & 16384) ? Wv : Wk;
  const int idx = flat & 16383;
  const float4 v0 = *(const float4*)(W + idx);
  const float4 v1 = *(const float4*)(W + idx + 4);
  const float x[8] = {v0.x,v0.y,v0.z,v0.w,v1.x,v1.y,v1.z,v1.w};
  unsigned int h[4], l[4];
  #pragma unroll
  for (int j = 0; j < 4; j++){
    const ushort_t h0 = f2bf(x[2*j]),   h1 = f2bf(x[2*j+1]);
    const ushort_t l0 = f2bf(x[2*j] - bf2f(h0)), l1 = f2bf(x[2*j+1] - bf2f(h1));
    h[j] = (unsigned int)h0 | ((unsigned int)h1 << 16);
    l[j] = (unsigned int)l0 | ((unsigned int)l1 << 16);
  }
  *(uint4*)(wh + flat) = make_uint4(h[0],h[1],h[2],h[3]);
  *(uint4*)(wl + flat) = make_uint4(l[0],l[1],l[2],l[3]);
}

// ---------------- K2: ekkT[c][n] via MFMA; 1D grid 256, XCD-swizzled.
__global__ __launch_bounds__(512) void k_kv_mfma(
    const ushort_t* __restrict__ nodes_hi, const ushort_t* __restrict__ nodes_lo,
    const ushort_t* __restrict__ wh, const ushort_t* __restrict__ wlp,
    ushort_t* __restrict__ ekkT_hi, ushort_t* __restrict__ ekkT_lo)
{
  extern __shared__ ushort_t st[];      // [256][136] = 69,632 B
  const int orig = xcd_swz(blockIdx.x, 16 * BB);
  const int b  = orig >> 4;
  const int n0 = (orig & 15) * 128;
  const int tid = threadIdx.x;
  const int w  = tid >> 6, l = tid & 63;
  const int wc = w >> 1;
  const int wn = w & 1;
  const int lr = l & 15;
  const int d0b = (l >> 4) * 8;

  f32x4 acc_k[2][4], acc_v[2][4];
  #pragma unroll
  for (int i = 0; i < 2; i++)
    #pragma unroll
    for (int j = 0; j < 4; j++){
      acc_k[i][j] = (f32x4){0.f,0.f,0.f,0.f};
      acc_v[i][j] = (f32x4){0.f,0.f,0.f,0.f};
    }

  #pragma unroll
  for (int kd = 0; kd < 4; kd++){
    const int d0 = kd * 32 + d0b;
    short8 akh[2], akl[2], avh[2], avl[2];
    #pragma unroll
    for (int tf = 0; tf < 2; tf++){
      const int c = wc * 32 + tf * 16 + lr;
      const size_t wo = (size_t)c * DD + d0;
      akh[tf] = *(const short8*)(wh  + wo);
      akl[tf] = *(const short8*)(wlp + wo);
      avh[tf] = *(const short8*)(wh  + 16384 + wo);
      avl[tf] = *(const short8*)(wlp + 16384 + wo);
    }
    short8 bh[4], bl[4];
    #pragma unroll
    for (int tn = 0; tn < 4; tn++){
      const int n = n0 + wn * 64 + tn * 16 + lr;
      const size_t no = ((size_t)b * KPAD + n) * DD + d0;
      bh[tn] = *(const short8*)(nodes_hi + no);
      bl[tn] = *(const short8*)(nodes_lo + no);
    }
    #pragma unroll
    for (int tf = 0; tf < 2; tf++)
      #pragma unroll
      for (int tn = 0; tn < 4; tn++){
        acc_k[tf][tn] = __builtin_amdgcn_mfma_f32_16x16x32_bf16(akh[tf], bh[tn], acc_k[tf][tn], 0, 0, 0);
        acc_k[tf][tn] = __builtin_amdgcn_mfma_f32_16x16x32_bf16(akh[tf], bl[tn], acc_k[tf][tn], 0, 0, 0);
        acc_k[tf][tn] = __builtin_amdgcn_mfma_f32_16x16x32_bf16(akl[tf], bh[tn], acc_k[tf][tn], 0, 0, 0);
        acc_v[tf][tn] = __builtin_amdgcn_mfma_f32_16x16x32_bf16(avh[tf], bh[tn], acc_v[tf][tn], 0, 0, 0);
        acc_v[tf][tn] = __builtin_amdgcn_mfma_f32_16x16x32_bf16(avh[tf], bl[tn], acc_v[tf][tn], 0, 0, 0);
        acc_v[tf][tn] = __builtin_amdgcn_mfma_f32_16x16x32_bf16(avl[tf], bh[tn], acc_v[tf][tn], 0, 0, 0);
      }
  }
  #pragma unroll
  for (int tf = 0; tf < 2; tf++)
    #pragma unroll
    for (int tn = 0; tn < 4; tn++)
      #pragma unroll
      for (int r = 0; r < 4; r++){
        const float ek = expf(acc_k[tf][tn][r]);
        acc_k[tf][tn][r] = ek;
        acc_v[tf][tn][r] = ek * acc_v[tf][tn][r];
      }
  #pragma unroll
  for (int plane = 0; plane < 2; plane++){
    __syncthreads();
    #pragma unroll
    for (int tf = 0; tf < 2; tf++)
      #pragma unroll
      for (int tn = 0; tn < 4; tn++)
        #pragma unroll
        for (int r = 0; r < 4; r++){
          const int row = wc * 32 + tf * 16 + (l >> 4) * 4 + r;
          const int col = wn * 64 + tn * 16 + lr;
          const float vv = acc_v[tf][tn][r];
          const float vk = acc_k[tf][tn][r];
          const ushort_t hv = f2bf(vv), hk = f2bf(vk);
          st[row * 136 + col]         = plane ? f2bf(vv - bf2f(hv)) : hv;
          st[(row + 128) * 136 + col] = plane ? f2bf(vk - bf2f(hk)) : hk;
        }
    __syncthreads();
    const int row = tid >> 1, seg = tid & 1;
    const uint4* src = (const uint4*)(st + row * 136 + seg * 64);
    ushort_t* dp = (plane ? ekkT_lo : ekkT_hi)
                 + ((size_t)b * 256 + row) * KPAD + n0 + seg * 64;
    uint4* dst4 = (uint4*)dp;
    #pragma unroll
    for (int j = 0; j < 8; j++) dst4[j] = src[j];
  }
}

// ---- k_aft_mfma staging registers + helpers (round-20 version, unchanged)
struct StageRegs { float4 dv[2][2]; float4 nv[2][2]; };

__device__ __forceinline__ void stage_load(
    const float* __restrict__ dist, const float* __restrict__ ninf,
    size_t bbase, int p0, int k0p, int tid, StageRegs& R)
{
  #pragma unroll
  for (int i = 0; i < 2; i++){
    const int flat = tid * 8 + i * 2048;
    const int pl_ = flat >> 7;
    const int kl_ = flat & 127;
    const int pg = p0 + pl_;
    const int kg = k0p + kl_;
    const bool ok = (pg < PP) && (kg + 8 <= NN);
    const size_t o = bbase + (size_t)(ok ? pg : 0) * NN + (ok ? kg : 0);
    R.dv[i][0] = *(const float4*)(dist + o);
    R.dv[i][1] = *(const float4*)(dist + o + 4);
    R.nv[i][0] = *(const float4*)(ninf + o);
    R.nv[i][1] = *(const float4*)(ninf + o + 4);
  }
}

__device__ __forceinline__ void stage_write(
    ushort_t* __restrict__ eh, ushort_t* __restrict__ el, float scale,
    int p0, int k0p, int tid, const StageRegs& R)
{
  #pragma unroll
  for (int i = 0; i < 2; i++){
    const int flat = tid * 8 + i * 2048;
    const int pl_ = flat >> 7;
    const int kl_ = flat & 127;
    const int pg = p0 + pl_;
    const int kg = k0p + kl_;
    const bool ok = (pg < PP) && (kg + 8 <= NN);
    float e[8];
    const float4 da = R.dv[i][0], db = R.dv[i][1];
    const float4 na = R.nv[i][0], nb = R.nv[i][1];
    e[0] = expf(na.x - scale*da.x); e[1] = expf(na.y - scale*da.y);
    e[2] = expf(na.z - scale*da.z); e[3] = expf(na.w - scale*da.w);
    e[4] = expf(nb.x - scale*db.x); e[5] = expf(nb.y - scale*db.y);
    e[6] = expf(nb.z - scale*db.z); e[7] = expf(nb.w - scale*db.w);
    if (!ok){
      #pragma unroll
      for (int j = 0; j < 8; j++) e[j] = 0.f;
    }
    unsigned int hw[4], lw[4];
    #pragma unroll
    for (int j = 0; j < 4; j++){
      const ushort_t h0 = f2bf(e[2*j]),   h1 = f2bf(e[2*j+1]);
      const ushort_t l0 = f2bf(e[2*j] - bf2f(h0)), l1 = f2bf(e[2*j+1] - bf2f(h1));
      hw[j] = (unsigned int)h0 | ((unsigned int)h1 << 16);
      lw[j] = (unsigned int)l0 | ((unsigned int)l1 << 16);
    }
    *(uint4*)(eh + pl_ * AST2 + kl_) = make_uint4(hw[0],hw[1],hw[2],hw[3]);
    *(uint4*)(el + pl_ * AST2 + kl_) = make_uint4(lw[0],lw[1],lw[2],lw[3]);
  }
}

__device__ __forceinline__ void aft_mfma_phase(
    const ushort_t* __restrict__ eh, const ushort_t* __restrict__ el,
    const ushort_t* const bph[4], const ushort_t* const bpl[4],
    int kgbase, int lr, int lk, f32x4 acc[2][4])
{
  #pragma unroll
  for (int kc = 0; kc < 4; kc++){
    const int ko = kc * 32;
    const int kg = kgbase + ko;
    short8 ah[2], al[2], bh[4], bl[4];
    #pragma unroll
    for (int tp = 0; tp < 2; tp++){
      const int row = tp * 16 + lr;
      ah[tp] = *(const short8*)(eh + row * AST2 + lk + ko);
      al[tp] = *(const short8*)(el + row * AST2 + lk + ko);
    }
    #pragma unroll
    for (int tc = 0; tc < 4; tc++){
      bh[tc] = *(const short8*)(bph[tc] + kg);
      bl[tc] = *(const short8*)(bpl[tc] + kg);
    }
    #pragma unroll
    for (int tp = 0; tp < 2; tp++)
      #pragma unroll
      for (int tc = 0; tc < 4; tc++){
        acc[tp][tc] = __builtin_amdgcn_mfma_f32_16x16x32_bf16(ah[tp], bh[tc], acc[tp][tc], 0, 0, 0);
        acc[tp][tc] = __builtin_amdgcn_mfma_f32_16x16x32_bf16(ah[tp], bl[tc], acc[tp][tc], 0, 0, 0);
        acc[tp][tc] = __builtin_amdgcn_mfma_f32_16x16x32_bf16(al[tp], bh[tc], acc[tp][tc], 0, 0, 0);
      }
  }
}

// ---------------- K3a: double-buffered 4-phase e_alpha + MFMA (round-20 version)
__global__ __launch_bounds__(256, 2) void k_aft_mfma(
    const float* __restrict__ dist, const float* __restrict__ ninf,
    const ushort_t* __restrict__ ekkT_hi, const ushort_t* __restrict__ ekkT_lo,
    const float* __restrict__ log_scale, const float* __restrict__ aft_alpha,
    float* __restrict__ partial)
{
  __shared__ ushort_t ea_h0[32 * AST2], ea_l0[32 * AST2];
  __shared__ ushort_t ea_h1[32 * AST2], ea_l1[32 * AST2];
  const int orig = xcd_swz(blockIdx.x, 32 * BB);
  const int b  = orig >> 5;
  const int t  = orig & 31;
  const int mi = t >> 2;
  const int ks = t & 3;
  const int tid = threadIdx.x;
  const int p0 = mi * 32;
  const int k0 = ks * 512;
  const float scale = log_scale[0] * aft_alpha[0];
  const int w  = tid >> 6;
  const int l  = tid & 63;
  const int lr = l & 15;
  const int lk = (l >> 4) * 8;
  const size_t bbase = (size_t)b * PP * NN;

  f32x4 acc[2][4];
  #pragma unroll
  for (int i = 0; i < 2; i++)
    #pragma unroll
    for (int j = 0; j < 4; j++) acc[i][j] = (f32x4){0.f, 0.f, 0.f, 0.f};

  const ushort_t* bph[4];
  const ushort_t* bpl[4];
  #pragma unroll
  for (int tc = 0; tc < 4; tc++){
    const int c = w * 64 + tc * 16 + lr;
    const size_t off = ((size_t)b * 256 + c) * KPAD + k0 + lk;
    bph[tc] = ekkT_hi + off;
    bpl[tc] = ekkT_lo + off;
  }

  StageRegs R;
  stage_load(dist, ninf, bbase, p0, k0, tid, R);
  stage_write(ea_h0, ea_l0, scale, p0, k0, tid, R);
  __syncthreads();

  stage_load(dist, ninf, bbase, p0, k0 + 128, tid, R);
  __builtin_amdgcn_sched_barrier(0);
  aft_mfma_phase(ea_h0, ea_l0, bph, bpl, 0, lr, lk, acc);
  __builtin_amdgcn_sched_barrier(0);
  stage_write(ea_h1, ea_l1, scale, p0, k0 + 128, tid, R);
  __syncthreads();

  stage_load(dist, ninf, bbase, p0, k0 + 256, tid, R);
  __builtin_amdgcn_sched_barrier(0);
  aft_mfma_phase(ea_h1, ea_l1, bph, bpl, 128, lr, lk, acc);
  __builtin_amdgcn_sched_barrier(0);
  stage_write(ea_h0, ea_l0, scale, p0, k0 + 256, tid, R);
  __syncthreads();

  stage_load(dist, ninf, bbase, p0, k0 + 384, tid, R);
  __builtin_amdgcn_sched_barrier(0);
  aft_mfma_phase(ea_h0, ea_l0, bph, bpl, 256, lr, lk, acc);
  __builtin_amdgcn_sched_barrier(0);
  stage_write(ea_h1, ea_l1, scale, p0, k0 + 384, tid, R);
  __syncthreads();

  aft_mfma_phase(ea_h1, ea_l1, bph, bpl, 384, lr, lk, acc);

  #pragma unroll
  for (int tp = 0; tp < 2; tp++){
    const int prow = p0 + tp * 16 + (l >> 4) * 4;
    #pragma unroll
    for (int tc = 0; tc < 4; tc++){
      const int c = w * 64 + tc * 16 + (l & 15);
      #pragma unroll
      for (int r = 0; r < 4; r++){
        partial[(size_t)ks * 1048576 + ((size_t)b * 256 + prow + r) * 256 + c] = acc[tp][tc][r];
      }
    }
  }
}

// ---------------- K3b: reduce 4 partials; aft = sq*bias/(den+eps) -> bf16 hi/lo
__global__ __launch_bounds__(256) void k_aft_reduce(
    const float* __restrict__ partial, const float* __restrict__ sq,
    ushort_t* __restrict__ aft_hi, ushort_t* __restrict__ aft_lo)
{
  const int pl = threadIdx.x >> 7;
  const int c  = threadIdx.x & 127;
  const int b = blockIdx.y;
  #pragma unroll
  for (int i = 0; i < 4; i++){
    const int p = blockIdx.x * 8 + i * 2 + pl;   // 0..255
    float v = 0.f;
    if (p < PP){
      const size_t base = ((size_t)b * 256 + p) * 256;
      float bias = 0.f, den = 0.f;
      #pragma unroll
      for (int ksi = 0; ksi < 4; ksi++){
        const float* ptr = partial + (size_t)ksi * 1048576 + base;
        bias += ptr[c];
        den  += ptr[c + 128];
      }
      v = sq[((size_t)b * PP + p) * DD + c] * (bias / (den + 1e-20f));
    }
    const size_t o = ((size_t)b * 256 + p) * DD + c;
    const ushort_t h = f2bf(v);
    aft_hi[o] = h;
    aft_lo[o] = f2bf(v - bf2f(h));
  }
}

// ---------------- K4a: pure score GEMM (raw dot products, f32 store).
// Tile 64p x 256n, 1D grid 512, XCD-swizzled. No epilogue math here.
__global__ __launch_bounds__(512) void k_score_gemm(
    const ushort_t* __restrict__ aft_hi, const ushort_t* __restrict__ aft_lo,
    const ushort_t* __restrict__ nodes_hi, const ushort_t* __restrict__ nodes_lo,
    float* __restrict__ score_out)
{
  const int orig = xcd_swz(blockIdx.x, 32 * BB);
  const int b  = orig >> 5;
  const int t  = orig & 31;
  const int mi = t >> 3;              // 0..3
  const int nt = t & 7;               // 0..7
  const int tid = threadIdx.x;
  const int p0 = mi * 64;
  const int n0 = nt * 256;
  const int w  = tid >> 6, l = tid & 63;
  const int wp = w >> 2, wc = w & 3;
  const int lr = l & 15, lk = (l >> 4) * 8;

  f32x4 acc[2][4];
  #pragma unroll
  for (int i = 0; i < 2; i++)
    #pragma unroll
    for (int j = 0; j < 4; j++) acc[i][j] = (f32x4){0.f, 0.f, 0.f, 0.f};

  const ushort_t* aph[2];
  const ushort_t* apl[2];
  #pragma unroll
  for (int tp = 0; tp < 2; tp++){
    const int row = p0 + wp * 32 + tp * 16 + lr;
    const size_t off = ((size_t)b * 256 + row) * DD + lk;
    aph[tp] = aft_hi + off;
    apl[tp] = aft_lo + off;
  }
  const ushort_t* bph[4];
  const ushort_t* bpl[4];
  #pragma unroll
  for (int tc = 0; tc < 4; tc++){
    const int n = n0 + wc * 64 + tc * 16 + lr;
    const size_t off = ((size_t)b * KPAD + n) * DD + lk;
    bph[tc] = nodes_hi + off;
    bpl[tc] = nodes_lo + off;
  }

  #pragma unroll
  for (int kc = 0; kc < 4; kc++){
    const int ko = kc * 32;
    short8 ah[2], al[2], bh[4], bl[4];
    #pragma unroll
    for (int tp = 0; tp < 2; tp++){
      ah[tp] = *(const short8*)(aph[tp] + ko);
      al[tp] = *(const short8*)(apl[tp] + ko);
    }
    #pragma unroll
    for (int tc = 0; tc < 4; tc++){
      bh[tc] = *(const short8*)(bph[tc] + ko);
      bl[tc] = *(const short8*)(bpl[tc] + ko);
    }
    #pragma unroll
    for (int tp = 0; tp < 2; tp++)
      #pragma unroll
      for (int tc = 0; tc < 4; tc++){
        acc[tp][tc] = __builtin_amdgcn_mfma_f32_16x16x32_bf16(ah[tp], bh[tc], acc[tp][tc], 0, 0, 0);
        acc[tp][tc] = __builtin_amdgcn_mfma_f32_16x16x32_bf16(ah[tp], bl[tc], acc[tp][tc], 0, 0, 0);
        acc[tp][tc] = __builtin_amdgcn_mfma_f32_16x16x32_bf16(al[tp], bh[tc], acc[tp][tc], 0, 0, 0);
        acc[tp][tc] = __builtin_amdgcn_mfma_f32_16x16x32_bf16(al[tp], bl[tc], acc[tp][tc], 0, 0, 0);
      }
  }
  // store raw dots
  #pragma unroll
  for (int tp = 0; tp < 2; tp++){
    #pragma unroll
    for (int r = 0; r < 4; r++){
      const int p = p0 + wp * 32 + tp * 16 + (l >> 4) * 4 + r;
      if (p < PP){
        #pragma unroll
        for (int tc = 0; tc < 4; tc++){
          const int ncol = n0 + wc * 64 + tc * 16 + (l & 15);
          if (ncol < NN)
            score_out[((size_t)b * PP + p) * NN + ncol] = acc[tp][tc][r];
        }
      }
    }
  }
}

// ---------------- K4b: fused epilogue + softmax. One (b,p) row per block.
// e = exp(10*tanh(s*isd - spb*d) + nf - 10); out = e / sum(e). Coalesced.
__global__ __launch_bounds__(256) void k_scale_fused(
    const float* __restrict__ score, const float* __restrict__ dist,
    const float* __restrict__ ninf, const float* __restrict__ log_scale,
    const float* __restrict__ probs_alpha, float* __restrict__ out)
{
  __shared__ float e_s[NN];           // 8000 B
  __shared__ float red[256];
  const int tid = threadIdx.x;
  const int p = blockIdx.x;
  const int b = blockIdx.y;
  const float spb = log_scale[0] * probs_alpha[0];
  const float isd = 0.088388347648318447f;  // 1/sqrt(128)
  const size_t base = ((size_t)b * PP + p) * NN;
  const float4* s4 = (const float4*)(score + base);
  const float4* d4 = (const float4*)(dist + base);
  const float4* n4 = (const float4*)(ninf + base);
  float4* es4 = (float4*)e_s;
  float psum = 0.f;
  for (int i = tid; i < NN / 4; i += 256){
    const float4 s = s4[i];
    const float4 d = d4[i];
    const float4 nf = n4[i];
    float4 e;
    e.x = expf(10.f * tanhf(s.x * isd - spb * d.x) + nf.x - 10.f);
    e.y = expf(10.f * tanhf(s.y * isd - spb * d.y) + nf.y - 10.f);
    e.z = expf(10.f * tanhf(s.z * isd - spb * d.z) + nf.z - 10.f);
    e.w = expf(10.f * tanhf(s.w * isd - spb * d.w) + nf.w - 10.f);
    es4[i] = e;
    psum += e.x + e.y + e.z + e.w;
  }
  red[tid] = psum;
  __syncthreads();
  for (int st = 128; st > 0; st >>= 1){
    if (tid < st) red[tid] += red[tid + st];
    __syncthreads();
  }
  const float inv = 1.f / red[0];
  float4* o4 = (float4*)(out + base);
  for (int i = tid; i < NN / 4; i += 256){
    float4 v = es4[i];
    v.x *= inv; v.y *= inv; v.z *= inv; v.w *= inv;
    o4[i] = v;
  }
}

extern "C" void kernel_launch(void* const* d_in, const int* in_sizes, int n_in,
                              void* d_out, int out_size, void* d_ws, size_t ws_size,
                              hipStream_t stream)
{
  const float* nodes = (const float*)d_in[0];
  const float* last  = (const float*)d_in[1];
  const float* q1    = (const float*)d_in[2];
  const float* q2    = (const float*)d_in[3];
  const float* loadv = (const float*)d_in[4];
  const float* leftv = (const float*)d_in[5];
  const float* dist  = (const float*)d_in[6];
  const float* ninf  = (const float*)d_in[7];
  const float* ls    = (const float*)d_in[8];
  const float* Wq1   = (const float*)d_in[9];
  const float* Wq2   = (const float*)d_in[10];
  const float* Wql   = (const float*)d_in[11];
  const float* Wk    = (const float*)d_in[12];
  const float* Wv    = (const float*)d_in[13];
  const float* aa    = (const float*)d_in[14];
  const float* pa    = (const float*)d_in[15];
  float* out = (float*)d_out;

  char* wsb = (char*)d_ws;
  float*    sq       = (float*)(wsb);                 // 1,638,400 B
  ushort_t* aft_hi   = (ushort_t*)(wsb + 1638400);    // 1,048,576 B
  ushort_t* aft_lo   = (ushort_t*)(wsb + 2686976);    // 1,048,576 B
  ushort_t* ekkT_hi  = (ushort_t*)(wsb + 3735552);    // 16,777,216 B
  ushort_t* ekkT_lo  = (ushort_t*)(wsb + 20512768);   // 16,777,216 B
  ushort_t* nodes_hi = (ushort_t*)(wsb + 37289984);   //  8,388,608 B
  ushort_t* nodes_lo = (ushort_t*)(wsb + 45678592);   //  8,388,608 B
  ushort_t* w_hi     = (ushort_t*)(wsb + 54067200);   //     65,536 B
  ushort_t* w_lo     = (ushort_t*)(wsb + 54132736);   //     65,536 B
  float*    partial  = (float*)(wsb + 54198272);      // 16,777,216 B [4][16][256][256]
  float*    score    = partial;                       // 25,600,000 B (partial dead)

  k_qproj<<<dim3((BB * PP) / 8), dim3(128), 0, stream>>>(q1, q2, last, loadv, leftv, Wq1, Wq2, Wql, sq);
  k_prep_nodes<<<dim3(2048), dim3(256), 0, stream>>>(nodes, nodes_hi, nodes_lo);
  k_prep_w<<<dim3(16), dim3(256), 0, stream>>>(Wk, Wv, w_hi, w_lo);
  k_kv_mfma<<<dim3(16 * BB), dim3(512), 69632, stream>>>(nodes_hi, nodes_lo, w_hi, w_lo, ekkT_hi, ekkT_lo);
  k_aft_mfma<<<dim3(32 * BB), dim3(256), 0, stream>>>(dist, ninf, ekkT_hi, ekkT_lo, ls, aa, partial);
  k_aft_reduce<<<dim3(32, BB), dim3(256), 0, stream>>>(partial, sq, aft_hi, aft_lo);
  k_score_gemm<<<dim3(32 * BB), dim3(512), 0, stream>>>(aft_hi, aft_lo, nodes_hi, nodes_lo, score);
  k_scale_fused<<<dim3(PP, BB), dim3(256), 0, stream>>>(score, dist, ninf, ls, pa, out);
}